// Round 22
// baseline (61.306 us; speedup 1.0000x reference)
//
#include <hip/hip_runtime.h>
#include <math.h>

#define BS 4096
#define C_CLS 16384
#define D 128
#define NS 16   // batch splits: each split = 256 rows = 4 rounds of 64
#define NR 4    // rounds per neg block
#define KE 46.16624130844683f
#define POS_C 4.616624130844683f  // 3.2/ln2
#define LN2 0.69314718055994531f
#define CORR_BLOCKS 256
#define NEG_BLOCKS 1024           // 64 pgs x 16 splits

typedef __attribute__((ext_vector_type(8))) short short8;
typedef __attribute__((ext_vector_type(16))) float f32x16;

__device__ inline float bf2f(unsigned short h) {
    return __uint_as_float(((unsigned)h) << 16);
}
__device__ inline unsigned short f2bf(float f) {
    unsigned u = __float_as_uint(f);
    u += 0x7FFF + ((u >> 16) & 1);  // RNE
    return (unsigned short)(u >> 16);
}
// Schraudolph fast exp2: full-rate VALU (fma + cvt), |rel err| <= 2.9%.
__device__ inline float fastexp2(float x) {
    return __int_as_float((int)fmaf(x, 8388608.0f, 1064866816.0f));
}
__device__ inline float softplus(float x) {
    return fmaxf(x, 0.0f) + log1pf(__expf(-fabsf(x)));
}
__device__ inline void gload16(const void* g, void* l) {
    __builtin_amdgcn_global_load_lds((const __attribute__((address_space(1))) void*)g,
                                     (__attribute__((address_space(3))) void*)l, 16, 0, 0);
}
__device__ inline unsigned fenc(float f) {
    unsigned u = __float_as_uint(f);
    return (u & 0x80000000u) ? ~u : (u | 0x80000000u);
}
__device__ inline float fdec(unsigned k) {
    return (k & 0x80000000u) ? __uint_as_float(k ^ 0x80000000u) : __uint_as_float(~k);
}

// ---------- normalize (batch unscaled, proxies x KE) + ws init ----------
__global__ __launch_bounds__(256) void normalize_all(const float* __restrict__ batch,
                                                     const float* __restrict__ proxies,
                                                     short* __restrict__ bbf,
                                                     short* __restrict__ pbf,
                                                     float* __restrict__ acc,
                                                     float* __restrict__ negSub,
                                                     float* __restrict__ posSum,
                                                     float* __restrict__ posCnt,
                                                     unsigned* __restrict__ posMaxK,
                                                     unsigned* __restrict__ posMinK,
                                                     int* __restrict__ counter) {
    const int sub = threadIdx.x >> 5;
    const int lane32 = threadIdx.x & 31;
    const int row = blockIdx.x * 8 + sub;
    const bool isb = row < BS;
    const float* src = isb ? batch : proxies;
    short* dst = isb ? bbf : pbf;
    const int r = isb ? row : row - BS;
    const float sc = isb ? 1.0f : KE;

    float4 v = ((const float4*)(src + (size_t)r * D))[lane32];
    float ss = v.x * v.x + v.y * v.y + v.z * v.z + v.w * v.w;
#pragma unroll
    for (int off = 16; off; off >>= 1) ss += __shfl_xor(ss, off);
    float inv = rsqrtf(ss) * sc;
    ushort4 o;
    o.x = f2bf(v.x * inv);
    o.y = f2bf(v.y * inv);
    o.z = f2bf(v.z * inv);
    o.w = f2bf(v.w * inv);
    ((ushort4*)(dst + (size_t)r * D))[lane32] = o;

    const int bid = blockIdx.x, t = threadIdx.x;
    if (bid < 64) negSub[bid * 256 + t] = 0.0f;
    else if (bid < 128) posSum[(bid - 64) * 256 + t] = 0.0f;
    else if (bid < 192) posCnt[(bid - 128) * 256 + t] = 0.0f;
    else if (bid < 256) posMaxK[(bid - 192) * 256 + t] = 0u;          // fenc(-inf)
    else if (bid < 320) posMinK[(bid - 256) * 256 + t] = 0xFFFFFFFFu; // fenc(+inf)
    if (bid == 0 && t == 0) *counter = 0;
}

// ---------- mm_all: corr blocks (first) + neg matmul (32x32x16 MFMA) ----------
// 32x32 shape: half the MFMA instructions; 4 chains of 8 (vs 16 chains of 4)
// -> 4x fewer MFMA->VALU chain-end sync points per round. A/B loaded with
// identical (lane,k) maps (internal k-permutation cancels); C/D mapping:
// col=lane&31, row=(reg&3)+8*(reg>>2)+4*(lane>>5) [m74/m101-verified].
__global__ __launch_bounds__(256, 1) void mm_all(const short* __restrict__ pbf,
                                                 const short* __restrict__ bbf,
                                                 const int* __restrict__ labels,
                                                 float* __restrict__ S,
                                                 float* __restrict__ negSub,
                                                 float* __restrict__ posSum,
                                                 float* __restrict__ posCnt,
                                                 unsigned* __restrict__ posMaxK,
                                                 unsigned* __restrict__ posMinK) {
    __shared__ short8 frag[2][16 * 64];  // 32KB

    const int bid = blockIdx.x;
    const int tid = threadIdx.x;
    const int w = tid >> 6, lane = tid & 63;

    if (bid < CORR_BLOCKS) {
        const int ibase = bid * 16 + w * 4;
        int lab[4];
        float d[4];
#pragma unroll
        for (int r = 0; r < 4; r++) {
            const int i = ibase + r;
            lab[r] = labels[i];
            ushort2 av = ((const ushort2*)(bbf + (size_t)i * D))[lane];
            ushort2 pv = ((const ushort2*)(pbf + (size_t)lab[r] * D))[lane];  // KE-scaled
            d[r] = bf2f(av.x) * bf2f(pv.x) + bf2f(av.y) * bf2f(pv.y);
        }
#pragma unroll
        for (int off = 32; off; off >>= 1)
#pragma unroll
            for (int r = 0; r < 4; r++) d[r] += __shfl_xor(d[r], off);

        if (lane == 0) {
#pragma unroll
            for (int r = 0; r < 4; r++) {
                atomicAdd(&negSub[lab[r]], fastexp2(d[r]));
                atomicAdd(&posSum[lab[r]], fastexp2(POS_C - d[r]));
                atomicAdd(&posCnt[lab[r]], 1.0f);
                unsigned k = fenc(fmaf(d[r], -LN2, 3.2f));
                atomicMax(&posMaxK[lab[r]], k);
                atomicMin(&posMinK[lab[r]], k);
            }
        }
        return;
    }

    // ---- neg matmul ----
    const int l32 = lane & 31, hi = lane >> 5;
    const int n = bid - CORR_BLOCKS;  // 0..1023
    const int pg = (n & 7) * 8 + ((n >> 3) & 7);  // bijective XCD swizzle, 0..63
    const int sp = n >> 6;                        // 0..15
    const int wbase = pg * 256 + w * 64;

    // A: 64 proxies = 2 tiles of 32 rows; lane holds row l32, k = kk*16 + hi*8
    short8 a[2][8];
#pragma unroll
    for (int pt = 0; pt < 2; pt++)
#pragma unroll
        for (int kk = 0; kk < 8; kk++)
            a[pt][kk] = *(const short8*)(pbf + (size_t)(wbase + pt * 32 + l32) * D + kk * 16 + hi * 8);
#pragma unroll
    for (int pt = 0; pt < 2; pt++)
#pragma unroll
        for (int kk = 0; kk < 8; kk++)
            asm volatile("" : "+v"(a[pt][kk]));  // keep-alive: A register-resident

    float s[2][16];
#pragma unroll
    for (int pt = 0; pt < 2; pt++)
#pragma unroll
        for (int r = 0; r < 16; r++) s[pt][r] = 0.0f;

    const int ibeg = sp * (BS / NS);

    // staging: 16 granule-groups/round; idx = cg*8 + kk; wave w stages idx = w*4..w*4+3
#define STAGE(rr)                                                                      \
    {                                                                                  \
        _Pragma("unroll") for (int jj = 0; jj < 4; jj++) {                             \
            const int idx_ = w * 4 + jj;                                               \
            const int cg_ = idx_ >> 3, kk_ = idx_ & 7;                                 \
            const short* sn_ = bbf +                                                   \
                (size_t)(ibeg + (rr) * 64 + cg_ * 32 + l32) * D + kk_ * 16 + hi * 8;   \
            gload16(sn_, &frag[(rr) & 1][idx_ * 64]);                                  \
        }                                                                              \
    }

    STAGE(0)
    asm volatile("s_waitcnt vmcnt(0)" ::: "memory");
    __syncthreads();

    for (int rnd = 0; rnd < NR; rnd++) {
        const int cur = rnd & 1;
        if (rnd + 1 < NR) STAGE(rnd + 1)  // into other buffer; readers passed barrier

        const short8* fb = &frag[cur][0];
#pragma unroll
        for (int cg = 0; cg < 2; cg++) {
            short8 b[8];
#pragma unroll
            for (int kk = 0; kk < 8; kk++) b[kk] = fb[(cg * 8 + kk) * 64 + lane];
#pragma unroll
            for (int pt = 0; pt < 2; pt++) {
                f32x16 acc = {0};
#pragma unroll
                for (int kk = 0; kk < 8; kk++)
                    acc = __builtin_amdgcn_mfma_f32_32x32x16_bf16(a[pt][kk], b[kk], acc, 0, 0, 0);
#pragma unroll
                for (int r = 0; r < 16; r++) s[pt][r] += fastexp2(acc[r]);
            }
        }
        asm volatile("s_waitcnt vmcnt(0)" ::: "memory");
        __syncthreads();
    }
#undef STAGE

    // reduce over the 32 batch-column lanes (within each 32-lane half)
#pragma unroll
    for (int off = 1; off < 32; off <<= 1)
#pragma unroll
        for (int pt = 0; pt < 2; pt++)
#pragma unroll
            for (int r = 0; r < 16; r++) s[pt][r] += __shfl_xor(s[pt][r], off);

    if (l32 == 0) {
        // C/D row mapping: row = (r&3) + 8*(r>>2) + 4*hi
#pragma unroll
        for (int pt = 0; pt < 2; pt++)
#pragma unroll
            for (int r = 0; r < 16; r++) {
                int row = wbase + pt * 32 + (r & 3) + 8 * (r >> 2) + 4 * hi;
                S[(size_t)sp * C_CLS + row] = s[pt][r];
            }
    }
}

// ---------- final: combine partials + softplus + mean; last block writes out ----------
__global__ __launch_bounds__(256) void final_reduce(const float* __restrict__ S,
                                                    const float* __restrict__ negSub,
                                                    const int* __restrict__ labels,
                                                    const float* __restrict__ posSum,
                                                    const float* __restrict__ posCnt,
                                                    const unsigned* __restrict__ posMaxK,
                                                    const unsigned* __restrict__ posMinK,
                                                    float* __restrict__ acc,
                                                    int* __restrict__ counter,
                                                    float* __restrict__ out) {
    const int n = blockIdx.x * 256 + threadIdx.x;
    float add = 0.0f, cnt = 0.0f;
    int slot;
    if (n < C_CLS) {
        slot = 2;
        float s = 0.0f;
#pragma unroll
        for (int p = 0; p < NS; p++) s += S[(size_t)p * C_CLS + n];
        s = fmaxf(s - negSub[n], 1e-30f);
        add = softplus(logf(s) + 3.2f);
        cnt = 1.0f;  // nz always true for neg (max>0, min<0, huge margins)
    } else {
        slot = 0;
        const int j = n - C_CLS;
        const int lab = labels[j];
        float s = posSum[lab], c = posCnt[lab];
        float mxw = fdec(posMaxK[lab]), mnw = fdec(posMinK[lab]);
        float maxm = (c < (float)BS) ? fmaxf(mxw, 0.0f) : mxw;
        float minm = (c < (float)BS) ? fminf(mnw, 0.0f) : mnw;
        bool nz = (maxm + minm) != 0.0f;
        if (nz) {
            add = softplus(logf(s));
            cnt = 1.0f;
        }
    }
#pragma unroll
    for (int off = 32; off; off >>= 1) {
        add += __shfl_xor(add, off);
        cnt += __shfl_xor(cnt, off);
    }
    if ((threadIdx.x & 63) == 0) {
        atomicAdd(&acc[slot], add);
        atomicAdd(&acc[slot + 1], cnt);
    }

    __shared__ int amLast;
    __threadfence();
    if (threadIdx.x == 0) amLast = (atomicAdd(counter, 1) == (int)gridDim.x - 1);
    __syncthreads();
    if (amLast && threadIdx.x == 0) {
        __threadfence();
        out[0] = acc[0] / fmaxf(acc[1], 1.0f) + acc[2] / fmaxf(acc[3], 1.0f);
    }
}

// ---------- launch ----------
extern "C" void kernel_launch(void* const* d_in, const int* in_sizes, int n_in,
                              void* d_out, int out_size, void* d_ws, size_t ws_size,
                              hipStream_t stream) {
    const float* batch = (const float*)d_in[0];
    const float* proxies = (const float*)d_in[1];
    const int* labels = (const int*)d_in[2];
    float* out = (float*)d_out;

    char* ws = (char*)d_ws;
    float* acc = (float*)ws;
    int* counter = (int*)(ws + 64);
    short* bbf = (short*)(ws + 256);
    short* pbf = (short*)(ws + 256 + (size_t)BS * D * 2);
    char* p = ws + 256 + (size_t)(BS + C_CLS) * D * 2;
    float* negS = (float*)p;          p += (size_t)C_CLS * NS * 4;
    float* negSub = (float*)p;        p += (size_t)C_CLS * 4;
    float* posSum = (float*)p;        p += (size_t)C_CLS * 4;
    float* posCnt = (float*)p;        p += (size_t)C_CLS * 4;
    unsigned* posMaxK = (unsigned*)p; p += (size_t)C_CLS * 4;
    unsigned* posMinK = (unsigned*)p;

    normalize_all<<<(BS + C_CLS) / 8, 256, 0, stream>>>(batch, proxies, bbf, pbf, acc,
                                                        negSub, posSum, posCnt, posMaxK,
                                                        posMinK, counter);
    mm_all<<<CORR_BLOCKS + NEG_BLOCKS, 256, 0, stream>>>(pbf, bbf, labels, negS, negSub,
                                                         posSum, posCnt, posMaxK, posMinK);
    final_reduce<<<(C_CLS + BS) / 256, 256, 0, stream>>>(negS, negSub, labels, posSum,
                                                         posCnt, posMaxK, posMinK,
                                                         acc, counter, out);
}

// Round 23
// 45.203 us; speedup vs baseline: 1.3562x; 1.3562x over previous
//
#include <hip/hip_runtime.h>
#include <math.h>

#define BS 4096
#define C_CLS 16384
#define D 128
#define NS 8    // batch splits: each split = 512 rows = 8 rounds of 64
#define NR 8    // rounds per neg block (A loaded once)
#define KE 46.16624130844683f
#define POS_C 4.616624130844683f  // 3.2/ln2
#define LN2 0.69314718055994531f
#define CORR_BLOCKS 256
#define NEG_BLOCKS 512            // 64 pgs x 8 splits; 768 total blocks

typedef __attribute__((ext_vector_type(8))) short short8;
typedef __attribute__((ext_vector_type(4))) float f32x4;

__device__ inline float bf2f(unsigned short h) {
    return __uint_as_float(((unsigned)h) << 16);
}
__device__ inline unsigned short f2bf(float f) {
    unsigned u = __float_as_uint(f);
    u += 0x7FFF + ((u >> 16) & 1);  // RNE
    return (unsigned short)(u >> 16);
}
// Schraudolph fast exp2: full-rate VALU (fma + cvt), |rel err| <= 2.9%.
__device__ inline float fastexp2(float x) {
    return __int_as_float((int)fmaf(x, 8388608.0f, 1064866816.0f));
}
__device__ inline float softplus(float x) {
    return fmaxf(x, 0.0f) + log1pf(__expf(-fabsf(x)));
}
__device__ inline void gload16(const void* g, void* l) {
    __builtin_amdgcn_global_load_lds((const __attribute__((address_space(1))) void*)g,
                                     (__attribute__((address_space(3))) void*)l, 16, 0, 0);
}
__device__ inline unsigned fenc(float f) {
    unsigned u = __float_as_uint(f);
    return (u & 0x80000000u) ? ~u : (u | 0x80000000u);
}
__device__ inline float fdec(unsigned k) {
    return (k & 0x80000000u) ? __uint_as_float(k ^ 0x80000000u) : __uint_as_float(~k);
}

// ---------- normalize (batch unscaled, proxies x KE) + ws init ----------
__global__ __launch_bounds__(256) void normalize_all(const float* __restrict__ batch,
                                                     const float* __restrict__ proxies,
                                                     short* __restrict__ bbf,
                                                     short* __restrict__ pbf,
                                                     float* __restrict__ acc,
                                                     float* __restrict__ negSub,
                                                     float* __restrict__ posSum,
                                                     float* __restrict__ posCnt,
                                                     unsigned* __restrict__ posMaxK,
                                                     unsigned* __restrict__ posMinK,
                                                     int* __restrict__ counter) {
    const int sub = threadIdx.x >> 5;
    const int lane32 = threadIdx.x & 31;
    const int row = blockIdx.x * 8 + sub;
    const bool isb = row < BS;
    const float* src = isb ? batch : proxies;
    short* dst = isb ? bbf : pbf;
    const int r = isb ? row : row - BS;
    const float sc = isb ? 1.0f : KE;

    float4 v = ((const float4*)(src + (size_t)r * D))[lane32];
    float ss = v.x * v.x + v.y * v.y + v.z * v.z + v.w * v.w;
#pragma unroll
    for (int off = 16; off; off >>= 1) ss += __shfl_xor(ss, off);
    float inv = rsqrtf(ss) * sc;
    ushort4 o;
    o.x = f2bf(v.x * inv);
    o.y = f2bf(v.y * inv);
    o.z = f2bf(v.z * inv);
    o.w = f2bf(v.w * inv);
    ((ushort4*)(dst + (size_t)r * D))[lane32] = o;

    const int bid = blockIdx.x, t = threadIdx.x;
    if (bid < 64) negSub[bid * 256 + t] = 0.0f;
    else if (bid < 128) posSum[(bid - 64) * 256 + t] = 0.0f;
    else if (bid < 192) posCnt[(bid - 128) * 256 + t] = 0.0f;
    else if (bid < 256) posMaxK[(bid - 192) * 256 + t] = 0u;          // fenc(-inf)
    else if (bid < 320) posMinK[(bid - 256) * 256 + t] = 0xFFFFFFFFu; // fenc(+inf)
    if (bid == 0 && t == 0) *counter = 0;
}

// ---------- mm_all: corr blocks (first) + neg matmul (batched-acc fold) ----------
// m97-pattern accumulators: per bt-PAIR, acc[2][4] = 8 INDEPENDENT MFMA chains
// in flight (vs 4 with immediate fold); exp-fold deferred to pair end so the
// next pair's independent MFMAs overlap the fold VALU. The one m97 element
// (acc[4][4] interleave) never previously ported.
__global__ __launch_bounds__(256, 1) void mm_all(const short* __restrict__ pbf,
                                                 const short* __restrict__ bbf,
                                                 const int* __restrict__ labels,
                                                 float* __restrict__ S,
                                                 float* __restrict__ negSub,
                                                 float* __restrict__ posSum,
                                                 float* __restrict__ posCnt,
                                                 unsigned* __restrict__ posMaxK,
                                                 unsigned* __restrict__ posMinK) {
    __shared__ short8 frag[2][16 * 64];  // 32KB

    const int bid = blockIdx.x;
    const int tid = threadIdx.x;
    const int w = tid >> 6, lane = tid & 63, l16 = lane & 15, g = lane >> 4;

    if (bid < CORR_BLOCKS) {
        const int ibase = bid * 16 + w * 4;
        int lab[4];
        float d[4];
#pragma unroll
        for (int r = 0; r < 4; r++) {
            const int i = ibase + r;
            lab[r] = labels[i];
            ushort2 av = ((const ushort2*)(bbf + (size_t)i * D))[lane];
            ushort2 pv = ((const ushort2*)(pbf + (size_t)lab[r] * D))[lane];  // KE-scaled
            d[r] = bf2f(av.x) * bf2f(pv.x) + bf2f(av.y) * bf2f(pv.y);
        }
#pragma unroll
        for (int off = 32; off; off >>= 1)
#pragma unroll
            for (int r = 0; r < 4; r++) d[r] += __shfl_xor(d[r], off);

        if (lane == 0) {
#pragma unroll
            for (int r = 0; r < 4; r++) {
                atomicAdd(&negSub[lab[r]], fastexp2(d[r]));
                atomicAdd(&posSum[lab[r]], fastexp2(POS_C - d[r]));
                atomicAdd(&posCnt[lab[r]], 1.0f);
                unsigned k = fenc(fmaf(d[r], -LN2, 3.2f));
                atomicMax(&posMaxK[lab[r]], k);
                atomicMin(&posMinK[lab[r]], k);
            }
        }
        return;
    }

    // ---- neg matmul ----
    const int n = bid - CORR_BLOCKS;  // 0..511
    const int pg = (n & 7) * 8 + ((n >> 3) & 7);  // bijective XCD swizzle
    const int sp = n >> 6;  // 0..7
    const int wbase = pg * 256 + w * 64;

    short8 a[4][4];
#pragma unroll
    for (int pt = 0; pt < 4; pt++)
#pragma unroll
        for (int kk = 0; kk < 4; kk++)
            a[pt][kk] = *(const short8*)(pbf + (size_t)(wbase + pt * 16 + l16) * D + kk * 32 + g * 8);
#pragma unroll
    for (int pt = 0; pt < 4; pt++)
#pragma unroll
        for (int kk = 0; kk < 4; kk++)
            asm volatile("" : "+v"(a[pt][kk]));  // keep-alive: A register-resident

    float s[4][4];
#pragma unroll
    for (int pt = 0; pt < 4; pt++)
#pragma unroll
        for (int r = 0; r < 4; r++) s[pt][r] = 0.0f;

    const int ibeg = sp * (BS / NS);
    const short* srcbase = bbf + (size_t)(ibeg + w * 16 + l16) * D + g * 8;

#define STAGE(rr)                                                            \
    {                                                                        \
        const short* sn_ = srcbase + (size_t)(rr) * 64 * D;                  \
        _Pragma("unroll") for (int kk = 0; kk < 4; kk++)                     \
            gload16(sn_ + kk * 32, &frag[(rr) & 1][(w * 4 + kk) * 64]);      \
    }

    STAGE(0)
    asm volatile("s_waitcnt vmcnt(0)" ::: "memory");
    __syncthreads();

    for (int rnd = 0; rnd < NR; rnd++) {
        const int cur = rnd & 1;
        if (rnd + 1 < NR) STAGE(rnd + 1)  // into other buffer; readers passed barrier

        const short8* fb = &frag[cur][0];
#pragma unroll
        for (int bth = 0; bth < 2; bth++) {
            // 8 independent accumulator chains (2 bt x 4 pt), fold deferred
            f32x4 pacc[2][4];
#pragma unroll
            for (int bi = 0; bi < 2; bi++)
#pragma unroll
                for (int pt = 0; pt < 4; pt++)
                    pacc[bi][pt] = (f32x4){0.0f, 0.0f, 0.0f, 0.0f};
#pragma unroll
            for (int bi = 0; bi < 2; bi++) {
                const int bt = bth * 2 + bi;
                short8 b[4];
#pragma unroll
                for (int kk = 0; kk < 4; kk++) b[kk] = fb[(bt * 4 + kk) * 64 + lane];
#pragma unroll
                for (int pt = 0; pt < 4; pt++)
#pragma unroll
                    for (int kk = 0; kk < 4; kk++)
                        pacc[bi][pt] = __builtin_amdgcn_mfma_f32_16x16x32_bf16(
                            a[pt][kk], b[kk], pacc[bi][pt], 0, 0, 0);
            }
            // fold 32 exps; next bth's MFMAs are independent of this VALU work
#pragma unroll
            for (int bi = 0; bi < 2; bi++)
#pragma unroll
                for (int pt = 0; pt < 4; pt++)
#pragma unroll
                    for (int r = 0; r < 4; r++)
                        s[pt][r] += fastexp2(pacc[bi][pt][r]);
        }
        asm volatile("s_waitcnt vmcnt(0)" ::: "memory");
        __syncthreads();
    }
#undef STAGE

    // reduce the 16 batch-column lanes (stays within g group)
#pragma unroll
    for (int off = 1; off < 16; off <<= 1)
#pragma unroll
        for (int pt = 0; pt < 4; pt++)
#pragma unroll
            for (int r = 0; r < 4; r++) s[pt][r] += __shfl_xor(s[pt][r], off);

    if (l16 == 0) {
        // transposed layout S[sp][row]: contiguous stores
#pragma unroll
        for (int pt = 0; pt < 4; pt++)
#pragma unroll
            for (int r = 0; r < 4; r++) {
                int row = wbase + pt * 16 + g * 4 + r;
                S[(size_t)sp * C_CLS + row] = s[pt][r];
            }
    }
}

// ---------- final: combine partials + softplus + mean; last block writes out ----------
__global__ __launch_bounds__(256) void final_reduce(const float* __restrict__ S,
                                                    const float* __restrict__ negSub,
                                                    const int* __restrict__ labels,
                                                    const float* __restrict__ posSum,
                                                    const float* __restrict__ posCnt,
                                                    const unsigned* __restrict__ posMaxK,
                                                    const unsigned* __restrict__ posMinK,
                                                    float* __restrict__ acc,
                                                    int* __restrict__ counter,
                                                    float* __restrict__ out) {
    const int n = blockIdx.x * 256 + threadIdx.x;
    float add = 0.0f, cnt = 0.0f;
    int slot;
    if (n < C_CLS) {
        slot = 2;
        float s = 0.0f;
#pragma unroll
        for (int p = 0; p < NS; p++) s += S[(size_t)p * C_CLS + n];
        s = fmaxf(s - negSub[n], 1e-30f);
        add = softplus(logf(s) + 3.2f);
        cnt = 1.0f;  // nz always true for neg (max>0, min<0, huge margins)
    } else {
        slot = 0;
        const int j = n - C_CLS;
        const int lab = labels[j];
        float s = posSum[lab], c = posCnt[lab];
        float mxw = fdec(posMaxK[lab]), mnw = fdec(posMinK[lab]);
        float maxm = (c < (float)BS) ? fmaxf(mxw, 0.0f) : mxw;
        float minm = (c < (float)BS) ? fminf(mnw, 0.0f) : mnw;
        bool nz = (maxm + minm) != 0.0f;
        if (nz) {
            add = softplus(logf(s));
            cnt = 1.0f;
        }
    }
#pragma unroll
    for (int off = 32; off; off >>= 1) {
        add += __shfl_xor(add, off);
        cnt += __shfl_xor(cnt, off);
    }
    if ((threadIdx.x & 63) == 0) {
        atomicAdd(&acc[slot], add);
        atomicAdd(&acc[slot + 1], cnt);
    }

    __shared__ int amLast;
    __threadfence();
    if (threadIdx.x == 0) amLast = (atomicAdd(counter, 1) == (int)gridDim.x - 1);
    __syncthreads();
    if (amLast && threadIdx.x == 0) {
        __threadfence();
        out[0] = acc[0] / fmaxf(acc[1], 1.0f) + acc[2] / fmaxf(acc[3], 1.0f);
    }
}

// ---------- launch ----------
extern "C" void kernel_launch(void* const* d_in, const int* in_sizes, int n_in,
                              void* d_out, int out_size, void* d_ws, size_t ws_size,
                              hipStream_t stream) {
    const float* batch = (const float*)d_in[0];
    const float* proxies = (const float*)d_in[1];
    const int* labels = (const int*)d_in[2];
    float* out = (float*)d_out;

    char* ws = (char*)d_ws;
    float* acc = (float*)ws;
    int* counter = (int*)(ws + 64);
    short* bbf = (short*)(ws + 256);
    short* pbf = (short*)(ws + 256 + (size_t)BS * D * 2);
    char* p = ws + 256 + (size_t)(BS + C_CLS) * D * 2;
    float* negS = (float*)p;          p += (size_t)C_CLS * NS * 4;
    float* negSub = (float*)p;        p += (size_t)C_CLS * 4;
    float* posSum = (float*)p;        p += (size_t)C_CLS * 4;
    float* posCnt = (float*)p;        p += (size_t)C_CLS * 4;
    unsigned* posMaxK = (unsigned*)p; p += (size_t)C_CLS * 4;
    unsigned* posMinK = (unsigned*)p;

    normalize_all<<<(BS + C_CLS) / 8, 256, 0, stream>>>(batch, proxies, bbf, pbf, acc,
                                                        negSub, posSum, posCnt, posMaxK,
                                                        posMinK, counter);
    mm_all<<<CORR_BLOCKS + NEG_BLOCKS, 256, 0, stream>>>(pbf, bbf, labels, negS, negSub,
                                                         posSum, posCnt, posMaxK, posMinK);
    final_reduce<<<(C_CLS + BS) / 256, 256, 0, stream>>>(negS, negSub, labels, posSum,
                                                         posCnt, posMaxK, posMinK,
                                                         acc, counter, out);
}

// Round 24
// 44.385 us; speedup vs baseline: 1.3812x; 1.0184x over previous
//
#include <hip/hip_runtime.h>
#include <math.h>

#define BS 4096
#define C_CLS 16384
#define D 128
#define NS 8    // batch splits: each split = 512 rows = 8 rounds of 64
#define NR 8    // rounds per neg block (A loaded once)
#define KE 46.16624130844683f
#define POS_C 4.616624130844683f  // 3.2/ln2
#define LN2 0.69314718055994531f
#define CORR_BLOCKS 256
#define NEG_BLOCKS 512            // 64 pgs x 8 splits

typedef __attribute__((ext_vector_type(8))) short short8;
typedef __attribute__((ext_vector_type(4))) float f32x4;

__device__ inline float bf2f(unsigned short h) {
    return __uint_as_float(((unsigned)h) << 16);
}
__device__ inline unsigned short f2bf(float f) {
    unsigned u = __float_as_uint(f);
    u += 0x7FFF + ((u >> 16) & 1);  // RNE
    return (unsigned short)(u >> 16);
}
// Schraudolph fast exp2: full-rate VALU (fma + cvt), |rel err| <= 2.9%.
__device__ inline float fastexp2(float x) {
    return __int_as_float((int)fmaf(x, 8388608.0f, 1064866816.0f));
}
__device__ inline float softplus(float x) {
    return fmaxf(x, 0.0f) + log1pf(__expf(-fabsf(x)));
}
__device__ inline void gload16(const void* g, void* l) {
    __builtin_amdgcn_global_load_lds((const __attribute__((address_space(1))) void*)g,
                                     (__attribute__((address_space(3))) void*)l, 16, 0, 0);
}
__device__ inline unsigned fenc(float f) {
    unsigned u = __float_as_uint(f);
    return (u & 0x80000000u) ? ~u : (u | 0x80000000u);
}
__device__ inline float fdec(unsigned k) {
    return (k & 0x80000000u) ? __uint_as_float(k ^ 0x80000000u) : __uint_as_float(~k);
}

// ---------- normalize (batch unscaled, proxies x KE) + ws init ----------
__global__ __launch_bounds__(256) void normalize_all(const float* __restrict__ batch,
                                                     const float* __restrict__ proxies,
                                                     short* __restrict__ bbf,
                                                     short* __restrict__ pbf,
                                                     float* __restrict__ acc,
                                                     float* __restrict__ negSub,
                                                     float* __restrict__ posSum,
                                                     float* __restrict__ posCnt,
                                                     unsigned* __restrict__ posMaxK,
                                                     unsigned* __restrict__ posMinK,
                                                     int* __restrict__ counter) {
    const int sub = threadIdx.x >> 5;
    const int lane32 = threadIdx.x & 31;
    const int row = blockIdx.x * 8 + sub;
    const bool isb = row < BS;
    const float* src = isb ? batch : proxies;
    short* dst = isb ? bbf : pbf;
    const int r = isb ? row : row - BS;
    const float sc = isb ? 1.0f : KE;

    float4 v = ((const float4*)(src + (size_t)r * D))[lane32];
    float ss = v.x * v.x + v.y * v.y + v.z * v.z + v.w * v.w;
#pragma unroll
    for (int off = 16; off; off >>= 1) ss += __shfl_xor(ss, off);
    float inv = rsqrtf(ss) * sc;
    ushort4 o;
    o.x = f2bf(v.x * inv);
    o.y = f2bf(v.y * inv);
    o.z = f2bf(v.z * inv);
    o.w = f2bf(v.w * inv);
    ((ushort4*)(dst + (size_t)r * D))[lane32] = o;

    const int bid = blockIdx.x, t = threadIdx.x;
    if (bid < 64) negSub[bid * 256 + t] = 0.0f;
    else if (bid < 128) posSum[(bid - 64) * 256 + t] = 0.0f;
    else if (bid < 192) posCnt[(bid - 128) * 256 + t] = 0.0f;
    else if (bid < 256) posMaxK[(bid - 192) * 256 + t] = 0u;          // fenc(-inf)
    else if (bid < 320) posMinK[(bid - 256) * 256 + t] = 0xFFFFFFFFu; // fenc(+inf)
    if (bid == 0 && t == 0) *counter = 0;
}

// ---------- mm_all: corr blocks (first) + neg matmul (3-ring counted vmcnt) ----------
// Clean T3/T4 retest (R7's only prior test ran under the (256,4) VGPR-clamp
// spill bug): 3-buffer LDS ring, stage rounds r+2 ahead, vmcnt(4) mid-loop
// (loads stay in flight ACROSS barriers), ONE barrier per round (vs 2 in the
// 2-buffer drain structure).
__global__ __launch_bounds__(256, 1) void mm_all(const short* __restrict__ pbf,
                                                 const short* __restrict__ bbf,
                                                 const int* __restrict__ labels,
                                                 float* __restrict__ S,
                                                 float* __restrict__ negSub,
                                                 float* __restrict__ posSum,
                                                 float* __restrict__ posCnt,
                                                 unsigned* __restrict__ posMaxK,
                                                 unsigned* __restrict__ posMinK) {
    __shared__ short8 frag[3][16 * 64];  // 48KB ring -> still 3 blocks/CU

    const int bid = blockIdx.x;
    const int tid = threadIdx.x;
    const int w = tid >> 6, lane = tid & 63, l16 = lane & 15, g = lane >> 4;

    if (bid < CORR_BLOCKS) {
        const int ibase = bid * 16 + w * 4;
        int lab[4];
        float d[4];
#pragma unroll
        for (int r = 0; r < 4; r++) {
            const int i = ibase + r;
            lab[r] = labels[i];
            ushort2 av = ((const ushort2*)(bbf + (size_t)i * D))[lane];
            ushort2 pv = ((const ushort2*)(pbf + (size_t)lab[r] * D))[lane];  // KE-scaled
            d[r] = bf2f(av.x) * bf2f(pv.x) + bf2f(av.y) * bf2f(pv.y);
        }
#pragma unroll
        for (int off = 32; off; off >>= 1)
#pragma unroll
            for (int r = 0; r < 4; r++) d[r] += __shfl_xor(d[r], off);

        if (lane == 0) {
#pragma unroll
            for (int r = 0; r < 4; r++) {
                atomicAdd(&negSub[lab[r]], fastexp2(d[r]));
                atomicAdd(&posSum[lab[r]], fastexp2(POS_C - d[r]));
                atomicAdd(&posCnt[lab[r]], 1.0f);
                unsigned k = fenc(fmaf(d[r], -LN2, 3.2f));
                atomicMax(&posMaxK[lab[r]], k);
                atomicMin(&posMinK[lab[r]], k);
            }
        }
        return;
    }

    // ---- neg matmul ----
    const int n = bid - CORR_BLOCKS;  // 0..511
    const int pg = (n & 7) * 8 + ((n >> 3) & 7);  // bijective XCD swizzle
    const int sp = n >> 6;  // 0..7
    const int wbase = pg * 256 + w * 64;

    short8 a[4][4];
#pragma unroll
    for (int pt = 0; pt < 4; pt++)
#pragma unroll
        for (int kk = 0; kk < 4; kk++)
            a[pt][kk] = *(const short8*)(pbf + (size_t)(wbase + pt * 16 + l16) * D + kk * 32 + g * 8);
#pragma unroll
    for (int pt = 0; pt < 4; pt++)
#pragma unroll
        for (int kk = 0; kk < 4; kk++)
            asm volatile("" : "+v"(a[pt][kk]));  // keep-alive: A register-resident

    float s[4][4];
#pragma unroll
    for (int pt = 0; pt < 4; pt++)
#pragma unroll
        for (int r = 0; r < 4; r++) s[pt][r] = 0.0f;

    const int ibeg = sp * (BS / NS);
    const short* srcbase = bbf + (size_t)(ibeg + w * 16 + l16) * D + g * 8;

#define STAGE(rr)                                                            \
    {                                                                        \
        const short* sn_ = srcbase + (size_t)(rr) * 64 * D;                  \
        _Pragma("unroll") for (int kk = 0; kk < 4; kk++)                     \
            gload16(sn_ + kk * 32, &frag[(rr) % 3][(w * 4 + kk) * 64]);      \
    }

    STAGE(0)
    STAGE(1)

    for (int rnd = 0; rnd < NR; rnd++) {
        // own round-rnd loads landed; round rnd+1 stays in flight (never 0 mid-loop)
        if (rnd < NR - 1)
            asm volatile("s_waitcnt vmcnt(4)" ::: "memory");
        else
            asm volatile("s_waitcnt vmcnt(0)" ::: "memory");
        __builtin_amdgcn_s_barrier();  // all waves' round-rnd data in LDS

        const short8* fb = &frag[rnd % 3][0];
#pragma unroll
        for (int bth = 0; bth < 2; bth++) {
            f32x4 pacc[2][4];
#pragma unroll
            for (int bi = 0; bi < 2; bi++)
#pragma unroll
                for (int pt = 0; pt < 4; pt++)
                    pacc[bi][pt] = (f32x4){0.0f, 0.0f, 0.0f, 0.0f};
#pragma unroll
            for (int bi = 0; bi < 2; bi++) {
                const int bt = bth * 2 + bi;
                short8 b[4];
#pragma unroll
                for (int kk = 0; kk < 4; kk++) b[kk] = fb[(bt * 4 + kk) * 64 + lane];
#pragma unroll
                for (int pt = 0; pt < 4; pt++)
#pragma unroll
                    for (int kk = 0; kk < 4; kk++)
                        pacc[bi][pt] = __builtin_amdgcn_mfma_f32_16x16x32_bf16(
                            a[pt][kk], b[kk], pacc[bi][pt], 0, 0, 0);
            }
#pragma unroll
            for (int bi = 0; bi < 2; bi++)
#pragma unroll
                for (int pt = 0; pt < 4; pt++)
#pragma unroll
                    for (int r = 0; r < 4; r++)
                        s[pt][r] += fastexp2(pacc[bi][pt][r]);
        }

        // prefetch 2 rounds ahead into frag[(rnd+2)%3] = frag[(rnd-1)%3]:
        // all waves finished reading it before barrier-rnd, which we passed.
        if (rnd + 2 < NR) STAGE(rnd + 2)
    }
#undef STAGE

    // reduce the 16 batch-column lanes (stays within g group)
#pragma unroll
    for (int off = 1; off < 16; off <<= 1)
#pragma unroll
        for (int pt = 0; pt < 4; pt++)
#pragma unroll
            for (int r = 0; r < 4; r++) s[pt][r] += __shfl_xor(s[pt][r], off);

    if (l16 == 0) {
        // transposed layout S[sp][row]: contiguous stores
#pragma unroll
        for (int pt = 0; pt < 4; pt++)
#pragma unroll
            for (int r = 0; r < 4; r++) {
                int row = wbase + pt * 16 + g * 4 + r;
                S[(size_t)sp * C_CLS + row] = s[pt][r];
            }
    }
}

// ---------- final: combine partials + softplus + mean; last block writes out ----------
__global__ __launch_bounds__(256) void final_reduce(const float* __restrict__ S,
                                                    const float* __restrict__ negSub,
                                                    const int* __restrict__ labels,
                                                    const float* __restrict__ posSum,
                                                    const float* __restrict__ posCnt,
                                                    const unsigned* __restrict__ posMaxK,
                                                    const unsigned* __restrict__ posMinK,
                                                    float* __restrict__ acc,
                                                    int* __restrict__ counter,
                                                    float* __restrict__ out) {
    const int n = blockIdx.x * 256 + threadIdx.x;
    float add = 0.0f, cnt = 0.0f;
    int slot;
    if (n < C_CLS) {
        slot = 2;
        float s = 0.0f;
#pragma unroll
        for (int p = 0; p < NS; p++) s += S[(size_t)p * C_CLS + n];
        s = fmaxf(s - negSub[n], 1e-30f);
        add = softplus(logf(s) + 3.2f);
        cnt = 1.0f;  // nz always true for neg (max>0, min<0, huge margins)
    } else {
        slot = 0;
        const int j = n - C_CLS;
        const int lab = labels[j];
        float s = posSum[lab], c = posCnt[lab];
        float mxw = fdec(posMaxK[lab]), mnw = fdec(posMinK[lab]);
        float maxm = (c < (float)BS) ? fmaxf(mxw, 0.0f) : mxw;
        float minm = (c < (float)BS) ? fminf(mnw, 0.0f) : mnw;
        bool nz = (maxm + minm) != 0.0f;
        if (nz) {
            add = softplus(logf(s));
            cnt = 1.0f;
        }
    }
#pragma unroll
    for (int off = 32; off; off >>= 1) {
        add += __shfl_xor(add, off);
        cnt += __shfl_xor(cnt, off);
    }
    if ((threadIdx.x & 63) == 0) {
        atomicAdd(&acc[slot], add);
        atomicAdd(&acc[slot + 1], cnt);
    }

    __shared__ int amLast;
    __threadfence();
    if (threadIdx.x == 0) amLast = (atomicAdd(counter, 1) == (int)gridDim.x - 1);
    __syncthreads();
    if (amLast && threadIdx.x == 0) {
        __threadfence();
        out[0] = acc[0] / fmaxf(acc[1], 1.0f) + acc[2] / fmaxf(acc[3], 1.0f);
    }
}

// ---------- launch ----------
extern "C" void kernel_launch(void* const* d_in, const int* in_sizes, int n_in,
                              void* d_out, int out_size, void* d_ws, size_t ws_size,
                              hipStream_t stream) {
    const float* batch = (const float*)d_in[0];
    const float* proxies = (const float*)d_in[1];
    const int* labels = (const int*)d_in[2];
    float* out = (float*)d_out;

    char* ws = (char*)d_ws;
    float* acc = (float*)ws;
    int* counter = (int*)(ws + 64);
    short* bbf = (short*)(ws + 256);
    short* pbf = (short*)(ws + 256 + (size_t)BS * D * 2);
    char* p = ws + 256 + (size_t)(BS + C_CLS) * D * 2;
    float* negS = (float*)p;          p += (size_t)C_CLS * NS * 4;
    float* negSub = (float*)p;        p += (size_t)C_CLS * 4;
    float* posSum = (float*)p;        p += (size_t)C_CLS * 4;
    float* posCnt = (float*)p;        p += (size_t)C_CLS * 4;
    unsigned* posMaxK = (unsigned*)p; p += (size_t)C_CLS * 4;
    unsigned* posMinK = (unsigned*)p;

    normalize_all<<<(BS + C_CLS) / 8, 256, 0, stream>>>(batch, proxies, bbf, pbf, acc,
                                                        negSub, posSum, posCnt, posMaxK,
                                                        posMinK, counter);
    mm_all<<<CORR_BLOCKS + NEG_BLOCKS, 256, 0, stream>>>(pbf, bbf, labels, negS, negSub,
                                                         posSum, posCnt, posMaxK, posMinK);
    final_reduce<<<(C_CLS + BS) / 256, 256, 0, stream>>>(negS, negSub, labels, posSum,
                                                         posCnt, posMaxK, posMinK,
                                                         acc, counter, out);
}